// Round 5
// baseline (266.526 us; speedup 1.0000x reference)
//
#include <hip/hip_runtime.h>

#define D  64    // feature dim (fixed by problem)
#define JB 256   // columns (x2 rows) per block = 4 waves * 64 lanes
#define IB 128   // x1 rows per block

typedef _Float16 h2    __attribute__((ext_vector_type(2)));
typedef unsigned u32x4 __attribute__((ext_vector_type(4)));

#define LOG2E_OVER_64 0.022542140772245335f
#define LOG2E_OVER_32 0.04508428154449067f

// ---- pre-kernel 1: convert x1,x2 fp32 -> fp16 (RTN) into workspace ----
__global__ void cvt_f32_to_f16(const float* __restrict__ x1,
                               const float* __restrict__ x2,
                               _Float16* __restrict__ x1h,
                               _Float16* __restrict__ x2h,
                               int n1, int n2)  // float counts
{
    int idx = blockIdx.x * blockDim.x + threadIdx.x;  // one idx = 4 floats
    int t1 = n1 / 4, tt = (n1 + n2) / 4;
    if (idx < t1) {
        float4 v = reinterpret_cast<const float4*>(x1)[idx];
        h2 lo = { (_Float16)v.x, (_Float16)v.y };
        h2 hi = { (_Float16)v.z, (_Float16)v.w };
        uint2 u = { __builtin_bit_cast(unsigned, lo), __builtin_bit_cast(unsigned, hi) };
        reinterpret_cast<uint2*>(x1h)[idx] = u;
    } else if (idx < tt) {
        int k = idx - t1;
        float4 v = reinterpret_cast<const float4*>(x2)[k];
        h2 lo = { (_Float16)v.x, (_Float16)v.y };
        h2 hi = { (_Float16)v.z, (_Float16)v.w };
        uint2 u = { __builtin_bit_cast(unsigned, lo), __builtin_bit_cast(unsigned, hi) };
        reinterpret_cast<uint2*>(x2h)[k] = u;
    }
}

// ---- pre-kernel 2: per-row sum of fp16 values, scaled by log2e/64 ----
__global__ void rowsum_f16(const _Float16* __restrict__ xh,
                           float* __restrict__ f, int nrows)
{
    int r = blockIdx.x * blockDim.x + threadIdx.x;
    if (r >= nrows) return;
    const uint4* p = reinterpret_cast<const uint4*>(xh + (size_t)r * D);
    float s = 0.f;
#pragma unroll
    for (int c = 0; c < 8; ++c) {
        uint4 v = p[c];
        h2 a = __builtin_bit_cast(h2, v.x); s += (float)a[0] + (float)a[1];
        h2 b = __builtin_bit_cast(h2, v.y); s += (float)b[0] + (float)b[1];
        h2 e = __builtin_bit_cast(h2, v.z); s += (float)e[0] + (float)e[1];
        h2 g = __builtin_bit_cast(h2, v.w); s += (float)g[0] + (float)g[1];
    }
    f[r] = s * LOG2E_OVER_64;
}

// ---- main kernel: min-trick L1; x1 rows streamed on the VECTOR pipe with
// counted vmcnt (in-order, never drained to 0), double-buffered in VGPRs.
// fa on SMEM depth-1 (single outstanding -> lgkmcnt(0) precise).
// S_ij = rsA_i + rsB_j - 2*sum_k min(a,b); out = exp2(M*log2e/32 - fA - fB).
__global__ __launch_bounds__(256, 4) void laplace_vmem_kernel(
    const _Float16* __restrict__ x1h, const _Float16* __restrict__ x2h,
    const float* __restrict__ fA, const float* __restrict__ fB,
    float* __restrict__ out, int n, int m)
{
    const int tid   = threadIdx.x;
    const int j     = blockIdx.x * JB + tid;
    const int ibase = blockIdx.y * IB;

    // Cache this lane's x2 row as 32 packed half2 words, pinned in VGPRs.
    unsigned bb[32];
    const u32x4* b4 = reinterpret_cast<const u32x4*>(x2h + (size_t)j * D);
#pragma unroll
    for (int c = 0; c < 8; ++c) {
        u32x4 v = b4[c];
        bb[4*c+0] = v[0]; bb[4*c+1] = v[1]; bb[4*c+2] = v[2]; bb[4*c+3] = v[3];
    }
#pragma unroll
    for (int q = 0; q < 32; ++q) asm volatile("" : "+v"(bb[q]));

    const float negfB = -fB[j];

    // Drain ALL compiler-issued VMEM before the counted pipeline starts, so
    // vmcnt bookkeeping below is exact.
    asm volatile("s_waitcnt vmcnt(0)" ::: "memory");
    __builtin_amdgcn_sched_barrier(0);

    const _Float16* apre = x1h + (size_t)ibase * D;              // uniform
    const float*    fp   = fA + ibase;                            // uniform
    float* ob = out + (size_t)ibase * m + (size_t)blockIdx.x * JB;// uniform

    unsigned vzero = 0;               // VGPR voffset for saddr-form loads
    unsigned voff  = (unsigned)tid * 4u;

    u32x4 rA[8], rB[8];
    float faA, faB;

#define LOAD8(BUF)                                                                                    \
    asm volatile("global_load_dwordx4 %0, %1, %2 offset:0"   : "=v"(BUF[0]) : "v"(vzero), "s"(apre)); \
    asm volatile("global_load_dwordx4 %0, %1, %2 offset:16"  : "=v"(BUF[1]) : "v"(vzero), "s"(apre)); \
    asm volatile("global_load_dwordx4 %0, %1, %2 offset:32"  : "=v"(BUF[2]) : "v"(vzero), "s"(apre)); \
    asm volatile("global_load_dwordx4 %0, %1, %2 offset:48"  : "=v"(BUF[3]) : "v"(vzero), "s"(apre)); \
    asm volatile("global_load_dwordx4 %0, %1, %2 offset:64"  : "=v"(BUF[4]) : "v"(vzero), "s"(apre)); \
    asm volatile("global_load_dwordx4 %0, %1, %2 offset:80"  : "=v"(BUF[5]) : "v"(vzero), "s"(apre)); \
    asm volatile("global_load_dwordx4 %0, %1, %2 offset:96"  : "=v"(BUF[6]) : "v"(vzero), "s"(apre)); \
    asm volatile("global_load_dwordx4 %0, %1, %2 offset:112" : "=v"(BUF[7]) : "v"(vzero), "s"(apre)); \
    apre += D;

    // Prologue: rows 0,1 in flight (16 loads), fa_0 in flight (1 SMEM).
    LOAD8(rA)
    LOAD8(rB)
    asm volatile("s_load_dword %0, %1, 0x0" : "=s"(faA) : "s"(fp)); fp += 1;

    // Body: wait(consumed buffer) -> compute -> store -> prefetch(+2 rows).
    // VMEM issue order per body = [store(1), loads(8)] => steady wait vmcnt(9).
#define ROWB(BUF, FC, FN, WAITS)                                                  \
    {                                                                             \
        asm volatile(WAITS);                                                      \
        __builtin_amdgcn_sched_barrier(0);                                        \
        asm volatile("s_waitcnt lgkmcnt(0)");                                     \
        __builtin_amdgcn_sched_barrier(0);                                        \
        asm volatile("s_load_dword %0, %1, 0x0" : "=s"(FN) : "s"(fp)); fp += 1;   \
        unsigned a0, a1, a2, a3, t0, t1, t2, t3;                                  \
        asm("v_pk_min_f16 %0, %1, %2" : "=v"(a0) : "v"(BUF[0][0]), "v"(bb[0]));   \
        asm("v_pk_min_f16 %0, %1, %2" : "=v"(a1) : "v"(BUF[0][1]), "v"(bb[1]));   \
        asm("v_pk_min_f16 %0, %1, %2" : "=v"(a2) : "v"(BUF[0][2]), "v"(bb[2]));   \
        asm("v_pk_min_f16 %0, %1, %2" : "=v"(a3) : "v"(BUF[0][3]), "v"(bb[3]));   \
        _Pragma("unroll")                                                         \
        for (int c = 1; c < 8; ++c) {                                             \
            asm("v_pk_min_f16 %0, %1, %2" : "=v"(t0) : "v"(BUF[c][0]), "v"(bb[4*c+0])); \
            asm("v_pk_add_f16 %0, %0, %1" : "+v"(a0) : "v"(t0));                  \
            asm("v_pk_min_f16 %0, %1, %2" : "=v"(t1) : "v"(BUF[c][1]), "v"(bb[4*c+1])); \
            asm("v_pk_add_f16 %0, %0, %1" : "+v"(a1) : "v"(t1));                  \
            asm("v_pk_min_f16 %0, %1, %2" : "=v"(t2) : "v"(BUF[c][2]), "v"(bb[4*c+2])); \
            asm("v_pk_add_f16 %0, %0, %1" : "+v"(a2) : "v"(t2));                  \
            asm("v_pk_min_f16 %0, %1, %2" : "=v"(t3) : "v"(BUF[c][3]), "v"(bb[4*c+3])); \
            asm("v_pk_add_f16 %0, %0, %1" : "+v"(a3) : "v"(t3));                  \
        }                                                                         \
        asm("v_pk_add_f16 %0, %0, %1" : "+v"(a0) : "v"(a1));                      \
        asm("v_pk_add_f16 %0, %0, %1" : "+v"(a2) : "v"(a3));                      \
        asm("v_pk_add_f16 %0, %0, %1" : "+v"(a0) : "v"(a2));                      \
        h2 r2 = __builtin_bit_cast(h2, a0);                                       \
        float Mf  = (float)r2[0] + (float)r2[1];                                  \
        float arg = fmaf(Mf, LOG2E_OVER_32, negfB) - FC;                          \
        float o   = __builtin_amdgcn_exp2f(arg);                                  \
        asm volatile("global_store_dword %0, %1, %2" :: "v"(voff), "v"(o), "s"(ob) : "memory"); \
        ob += m;                                                                  \
        LOAD8(BUF)                                                                \
    }

    ROWB(rA, faA, faB, "s_waitcnt vmcnt(8)")
    ROWB(rB, faB, faA, "s_waitcnt vmcnt(9)")
    for (int ii = 1; ii < IB / 2; ++ii) {
        ROWB(rA, faA, faB, "s_waitcnt vmcnt(9)")
        ROWB(rB, faB, faA, "s_waitcnt vmcnt(9)")
    }
#undef ROWB
#undef LOAD8
}

// ---- fallback (ws too small): fp32 kernel with pinned b ----
__global__ __launch_bounds__(256, 4) void laplace_f32_kernel(
    const float* __restrict__ x1, const float* __restrict__ x2,
    float* __restrict__ out, int n, int m)
{
    const int j     = blockIdx.x * JB + threadIdx.x;
    const int ibase = blockIdx.y * 256;

    float b[D];
    const float4* x2r = reinterpret_cast<const float4*>(x2 + (size_t)j * D);
#pragma unroll
    for (int q = 0; q < D / 4; ++q) {
        float4 v = x2r[q];
        b[4*q+0] = v.x; b[4*q+1] = v.y; b[4*q+2] = v.z; b[4*q+3] = v.w;
    }
#pragma unroll
    for (int q = 0; q < D; ++q) asm volatile("" : "+v"(b[q]));

    for (int i = ibase; i < ibase + 256; ++i) {
        const float4* a4 = reinterpret_cast<const float4*>(x1 + (size_t)i * D);
        float acc0 = 0.f, acc1 = 0.f, acc2 = 0.f, acc3 = 0.f;
#pragma unroll
        for (int q = 0; q < D / 4; ++q) {
            float4 av = a4[q];
            acc0 += fabsf(av.x - b[4*q+0]);
            acc1 += fabsf(av.y - b[4*q+1]);
            acc2 += fabsf(av.z - b[4*q+2]);
            acc3 += fabsf(av.w - b[4*q+3]);
        }
        float s = (acc0 + acc1) + (acc2 + acc3);
        out[(size_t)i * m + j] = __expf(s * -0.015625f);
    }
}

extern "C" void kernel_launch(void* const* d_in, const int* in_sizes, int n_in,
                              void* d_out, int out_size, void* d_ws, size_t ws_size,
                              hipStream_t stream)
{
    const float* x1 = (const float*)d_in[0];
    const float* x2 = (const float*)d_in[1];
    float* out = (float*)d_out;
    const int n = in_sizes[0] / D;   // 8192
    const int m = in_sizes[1] / D;   // 8192

    const size_t half_bytes = ((size_t)n + (size_t)m) * D * sizeof(_Float16);  // 2 MB
    const size_t need = half_bytes + ((size_t)n + (size_t)m) * sizeof(float);  // +64 KB
    if (ws_size >= need) {
        _Float16* x1h = (_Float16*)d_ws;
        _Float16* x2h = x1h + (size_t)n * D;
        float* fA = (float*)((char*)d_ws + half_bytes);
        float* fB = fA + n;

        const int total4 = (in_sizes[0] + in_sizes[1]) / 4;
        cvt_f32_to_f16<<<(total4 + 255) / 256, 256, 0, stream>>>(
            x1, x2, x1h, x2h, in_sizes[0], in_sizes[1]);
        rowsum_f16<<<(n + 255) / 256, 256, 0, stream>>>(x1h, fA, n);
        rowsum_f16<<<(m + 255) / 256, 256, 0, stream>>>(x2h, fB, m);

        dim3 grid(m / JB, n / IB);   // 32 x 64 = 2048 blocks
        laplace_vmem_kernel<<<grid, 256, 0, stream>>>(x1h, x2h, fA, fB, out, n, m);
    } else {
        dim3 grid(m / JB, n / 256); // 32 x 32
        laplace_f32_kernel<<<grid, 256, 0, stream>>>(x1, x2, out, n, m);
    }
}

// Round 6
// 165.106 us; speedup vs baseline: 1.6143x; 1.6143x over previous
//
#include <hip/hip_runtime.h>

#define D   64    // feature dim (fixed by problem)
#define JBL 512   // j columns per block = 2 per lane x 256 threads
#define IB  64    // x1 rows per block

typedef _Float16 h2    __attribute__((ext_vector_type(2)));
typedef unsigned u32x4 __attribute__((ext_vector_type(4)));

#define LOG2E_OVER_64 0.022542140772245335f
#define LOG2E_OVER_32 0.04508428154449067f

// ---- pre-kernel 1: convert x1,x2 fp32 -> fp16 (RTN) into workspace ----
__global__ void cvt_f32_to_f16(const float* __restrict__ x1,
                               const float* __restrict__ x2,
                               _Float16* __restrict__ x1h,
                               _Float16* __restrict__ x2h,
                               int n1, int n2)  // float counts
{
    int idx = blockIdx.x * blockDim.x + threadIdx.x;  // one idx = 4 floats
    int t1 = n1 / 4, tt = (n1 + n2) / 4;
    if (idx < t1) {
        float4 v = reinterpret_cast<const float4*>(x1)[idx];
        h2 lo = { (_Float16)v.x, (_Float16)v.y };
        h2 hi = { (_Float16)v.z, (_Float16)v.w };
        uint2 u = { __builtin_bit_cast(unsigned, lo), __builtin_bit_cast(unsigned, hi) };
        reinterpret_cast<uint2*>(x1h)[idx] = u;
    } else if (idx < tt) {
        int k = idx - t1;
        float4 v = reinterpret_cast<const float4*>(x2)[k];
        h2 lo = { (_Float16)v.x, (_Float16)v.y };
        h2 hi = { (_Float16)v.z, (_Float16)v.w };
        uint2 u = { __builtin_bit_cast(unsigned, lo), __builtin_bit_cast(unsigned, hi) };
        reinterpret_cast<uint2*>(x2h)[k] = u;
    }
}

// ---- pre-kernel 2: per-row sum of fp16 values, scaled by log2e/64 ----
__global__ void rowsum_f16(const _Float16* __restrict__ xh,
                           float* __restrict__ f, int nrows)
{
    int r = blockIdx.x * blockDim.x + threadIdx.x;
    if (r >= nrows) return;
    const uint4* p = reinterpret_cast<const uint4*>(xh + (size_t)r * D);
    float s = 0.f;
#pragma unroll
    for (int c = 0; c < 8; ++c) {
        uint4 v = p[c];
        h2 a = __builtin_bit_cast(h2, v.x); s += (float)a[0] + (float)a[1];
        h2 b = __builtin_bit_cast(h2, v.y); s += (float)b[0] + (float)b[1];
        h2 e = __builtin_bit_cast(h2, v.z); s += (float)e[0] + (float)e[1];
        h2 g = __builtin_bit_cast(h2, v.w); s += (float)g[0] + (float)g[1];
    }
    f[r] = s * LOG2E_OVER_64;
}

// ---- main kernel: min-trick L1, TWO x2 rows per lane (JBL=512) so each
// loaded x1 row feeds 126 pk-ops -> body ~300 cyc; 2-body vmcnt slack ~600cyc
// covers L2 load latency AND store-ack (round-5 failure mode).
// S_ij = rsA_i + rsB_j - 2*sum_k min(a,b); out = exp2(M*log2e/32 - fA - fB).
__global__ __launch_bounds__(256, 3) void laplace_wide_kernel(
    const _Float16* __restrict__ x1h, const _Float16* __restrict__ x2h,
    const float* __restrict__ fA, const float* __restrict__ fB,
    float* __restrict__ out, int n, int m)
{
    const int tid   = threadIdx.x;
    const int j0    = blockIdx.x * JBL + tid;
    const int j1    = j0 + 256;
    const int ibase = blockIdx.y * IB;

    // Cache TWO x2 rows per lane (64 packed half2 words), pinned in VGPRs.
    unsigned bbL[32], bbH[32];
    {
        const u32x4* p0 = reinterpret_cast<const u32x4*>(x2h + (size_t)j0 * D);
        const u32x4* p1 = reinterpret_cast<const u32x4*>(x2h + (size_t)j1 * D);
#pragma unroll
        for (int c = 0; c < 8; ++c) {
            u32x4 v0 = p0[c];
            bbL[4*c+0] = v0[0]; bbL[4*c+1] = v0[1]; bbL[4*c+2] = v0[2]; bbL[4*c+3] = v0[3];
            u32x4 v1 = p1[c];
            bbH[4*c+0] = v1[0]; bbH[4*c+1] = v1[1]; bbH[4*c+2] = v1[2]; bbH[4*c+3] = v1[3];
        }
    }
#pragma unroll
    for (int q = 0; q < 32; ++q) asm volatile("" : "+v"(bbL[q]), "+v"(bbH[q]));

    float negfB0 = -fB[j0];
    float negfB1 = -fB[j1];
    asm volatile("" : "+v"(negfB0), "+v"(negfB1));  // force materialization now

    // Drain ALL compiler-issued VMEM so the counted pipeline below is exact.
    asm volatile("s_waitcnt vmcnt(0)" ::: "memory");
    __builtin_amdgcn_sched_barrier(0);

    const _Float16* apre = x1h + (size_t)ibase * D;               // uniform
    const float*    fp   = fA + ibase;                             // uniform
    float* ob = out + (size_t)ibase * m + (size_t)blockIdx.x * JBL;// uniform

    unsigned vzero = 0;              // VGPR voffset for saddr-form loads
    unsigned voff  = (unsigned)tid * 4u;

    u32x4 rA[8], rB[8];
    float faA, faB;

#define LOAD8(BUF)                                                                                    \
    asm volatile("global_load_dwordx4 %0, %1, %2 offset:0"   : "=v"(BUF[0]) : "v"(vzero), "s"(apre)); \
    asm volatile("global_load_dwordx4 %0, %1, %2 offset:16"  : "=v"(BUF[1]) : "v"(vzero), "s"(apre)); \
    asm volatile("global_load_dwordx4 %0, %1, %2 offset:32"  : "=v"(BUF[2]) : "v"(vzero), "s"(apre)); \
    asm volatile("global_load_dwordx4 %0, %1, %2 offset:48"  : "=v"(BUF[3]) : "v"(vzero), "s"(apre)); \
    asm volatile("global_load_dwordx4 %0, %1, %2 offset:64"  : "=v"(BUF[4]) : "v"(vzero), "s"(apre)); \
    asm volatile("global_load_dwordx4 %0, %1, %2 offset:80"  : "=v"(BUF[5]) : "v"(vzero), "s"(apre)); \
    asm volatile("global_load_dwordx4 %0, %1, %2 offset:96"  : "=v"(BUF[6]) : "v"(vzero), "s"(apre)); \
    asm volatile("global_load_dwordx4 %0, %1, %2 offset:112" : "=v"(BUF[7]) : "v"(vzero), "s"(apre)); \
    apre += D;

    // Prologue: rows 0,1 in flight (16 loads), fa_0 in flight (1 SMEM).
    LOAD8(rA)
    LOAD8(rB)
    asm volatile("s_load_dword %0, %1, 0x0" : "=s"(faA) : "s"(fp)); fp += 1;

    // Body: wait(consumed row) -> compute 2 columns -> 2 stores -> prefetch.
    // VMEM issue per body = [st, st, L8] = 10 => steady wait vmcnt(10):
    // retires the consumed row's 8 loads + the 2 stores from 2 bodies ago
    // (~600 cyc old). Loads consumed are ~600 cyc old too.
#define ROWB(BUF, FC, FN, WAITS)                                                        \
    {                                                                                   \
        asm volatile(WAITS);                                                            \
        __builtin_amdgcn_sched_barrier(0);                                              \
        asm volatile("s_waitcnt lgkmcnt(0)");                                           \
        __builtin_amdgcn_sched_barrier(0);                                              \
        asm volatile("s_load_dword %0, %1, 0x0" : "=s"(FN) : "s"(fp)); fp += 1;         \
        unsigned aL0,aL1,aL2,aL3, aH0,aH1,aH2,aH3, t0,t1;                               \
        asm("v_pk_min_f16 %0, %1, %2" : "=v"(aL0) : "v"(BUF[0][0]), "v"(bbL[0]));       \
        asm("v_pk_min_f16 %0, %1, %2" : "=v"(aH0) : "v"(BUF[0][0]), "v"(bbH[0]));       \
        asm("v_pk_min_f16 %0, %1, %2" : "=v"(aL1) : "v"(BUF[0][1]), "v"(bbL[1]));       \
        asm("v_pk_min_f16 %0, %1, %2" : "=v"(aH1) : "v"(BUF[0][1]), "v"(bbH[1]));       \
        asm("v_pk_min_f16 %0, %1, %2" : "=v"(aL2) : "v"(BUF[0][2]), "v"(bbL[2]));       \
        asm("v_pk_min_f16 %0, %1, %2" : "=v"(aH2) : "v"(BUF[0][2]), "v"(bbH[2]));       \
        asm("v_pk_min_f16 %0, %1, %2" : "=v"(aL3) : "v"(BUF[0][3]), "v"(bbL[3]));       \
        asm("v_pk_min_f16 %0, %1, %2" : "=v"(aH3) : "v"(BUF[0][3]), "v"(bbH[3]));       \
        _Pragma("unroll")                                                               \
        for (int c = 1; c < 8; ++c) {                                                   \
            asm("v_pk_min_f16 %0, %1, %2" : "=v"(t0) : "v"(BUF[c][0]), "v"(bbL[4*c+0]));\
            asm("v_pk_add_f16 %0, %0, %1" : "+v"(aL0) : "v"(t0));                       \
            asm("v_pk_min_f16 %0, %1, %2" : "=v"(t1) : "v"(BUF[c][0]), "v"(bbH[4*c+0]));\
            asm("v_pk_add_f16 %0, %0, %1" : "+v"(aH0) : "v"(t1));                       \
            asm("v_pk_min_f16 %0, %1, %2" : "=v"(t0) : "v"(BUF[c][1]), "v"(bbL[4*c+1]));\
            asm("v_pk_add_f16 %0, %0, %1" : "+v"(aL1) : "v"(t0));                       \
            asm("v_pk_min_f16 %0, %1, %2" : "=v"(t1) : "v"(BUF[c][1]), "v"(bbH[4*c+1]));\
            asm("v_pk_add_f16 %0, %0, %1" : "+v"(aH1) : "v"(t1));                       \
            asm("v_pk_min_f16 %0, %1, %2" : "=v"(t0) : "v"(BUF[c][2]), "v"(bbL[4*c+2]));\
            asm("v_pk_add_f16 %0, %0, %1" : "+v"(aL2) : "v"(t0));                       \
            asm("v_pk_min_f16 %0, %1, %2" : "=v"(t1) : "v"(BUF[c][2]), "v"(bbH[4*c+2]));\
            asm("v_pk_add_f16 %0, %0, %1" : "+v"(aH2) : "v"(t1));                       \
            asm("v_pk_min_f16 %0, %1, %2" : "=v"(t0) : "v"(BUF[c][3]), "v"(bbL[4*c+3]));\
            asm("v_pk_add_f16 %0, %0, %1" : "+v"(aL3) : "v"(t0));                       \
            asm("v_pk_min_f16 %0, %1, %2" : "=v"(t1) : "v"(BUF[c][3]), "v"(bbH[4*c+3]));\
            asm("v_pk_add_f16 %0, %0, %1" : "+v"(aH3) : "v"(t1));                       \
        }                                                                               \
        asm("v_pk_add_f16 %0, %0, %1" : "+v"(aL0) : "v"(aL1));                          \
        asm("v_pk_add_f16 %0, %0, %1" : "+v"(aL2) : "v"(aL3));                          \
        asm("v_pk_add_f16 %0, %0, %1" : "+v"(aL0) : "v"(aL2));                          \
        asm("v_pk_add_f16 %0, %0, %1" : "+v"(aH0) : "v"(aH1));                          \
        asm("v_pk_add_f16 %0, %0, %1" : "+v"(aH2) : "v"(aH3));                          \
        asm("v_pk_add_f16 %0, %0, %1" : "+v"(aH0) : "v"(aH2));                          \
        h2 rL = __builtin_bit_cast(h2, aL0);                                            \
        h2 rH = __builtin_bit_cast(h2, aH0);                                            \
        float MfL = (float)rL[0] + (float)rL[1];                                        \
        float MfH = (float)rH[0] + (float)rH[1];                                        \
        float g0  = fmaf(MfL, LOG2E_OVER_32, negfB0) - FC;                              \
        float g1  = fmaf(MfH, LOG2E_OVER_32, negfB1) - FC;                              \
        float o0  = __builtin_amdgcn_exp2f(g0);                                         \
        float o1  = __builtin_amdgcn_exp2f(g1);                                         \
        asm volatile("global_store_dword %0, %1, %2"             :: "v"(voff), "v"(o0), "s"(ob) : "memory"); \
        asm volatile("global_store_dword %0, %1, %2 offset:1024" :: "v"(voff), "v"(o1), "s"(ob) : "memory"); \
        ob += m;                                                                        \
        LOAD8(BUF)                                                                      \
    }

    ROWB(rA, faA, faB, "s_waitcnt vmcnt(8)")
    ROWB(rB, faB, faA, "s_waitcnt vmcnt(10)")
    for (int ii = 1; ii < IB / 2; ++ii) {
        ROWB(rA, faA, faB, "s_waitcnt vmcnt(10)")
        ROWB(rB, faB, faA, "s_waitcnt vmcnt(10)")
    }
#undef ROWB
#undef LOAD8
}

// ---- fallback (ws too small): fp32 kernel with pinned b ----
__global__ __launch_bounds__(256, 4) void laplace_f32_kernel(
    const float* __restrict__ x1, const float* __restrict__ x2,
    float* __restrict__ out, int n, int m)
{
    const int j     = blockIdx.x * 256 + threadIdx.x;
    const int ibase = blockIdx.y * 256;

    float b[D];
    const float4* x2r = reinterpret_cast<const float4*>(x2 + (size_t)j * D);
#pragma unroll
    for (int q = 0; q < D / 4; ++q) {
        float4 v = x2r[q];
        b[4*q+0] = v.x; b[4*q+1] = v.y; b[4*q+2] = v.z; b[4*q+3] = v.w;
    }
#pragma unroll
    for (int q = 0; q < D; ++q) asm volatile("" : "+v"(b[q]));

    for (int i = ibase; i < ibase + 256; ++i) {
        const float4* a4 = reinterpret_cast<const float4*>(x1 + (size_t)i * D);
        float acc0 = 0.f, acc1 = 0.f, acc2 = 0.f, acc3 = 0.f;
#pragma unroll
        for (int q = 0; q < D / 4; ++q) {
            float4 av = a4[q];
            acc0 += fabsf(av.x - b[4*q+0]);
            acc1 += fabsf(av.y - b[4*q+1]);
            acc2 += fabsf(av.z - b[4*q+2]);
            acc3 += fabsf(av.w - b[4*q+3]);
        }
        float s = (acc0 + acc1) + (acc2 + acc3);
        out[(size_t)i * m + j] = __expf(s * -0.015625f);
    }
}

extern "C" void kernel_launch(void* const* d_in, const int* in_sizes, int n_in,
                              void* d_out, int out_size, void* d_ws, size_t ws_size,
                              hipStream_t stream)
{
    const float* x1 = (const float*)d_in[0];
    const float* x2 = (const float*)d_in[1];
    float* out = (float*)d_out;
    const int n = in_sizes[0] / D;   // 8192
    const int m = in_sizes[1] / D;   // 8192

    const size_t half_bytes = ((size_t)n + (size_t)m) * D * sizeof(_Float16);  // 2 MB
    const size_t need = half_bytes + ((size_t)n + (size_t)m) * sizeof(float);  // +64 KB
    if (ws_size >= need) {
        _Float16* x1h = (_Float16*)d_ws;
        _Float16* x2h = x1h + (size_t)n * D;
        float* fA = (float*)((char*)d_ws + half_bytes);
        float* fB = fA + n;

        const int total4 = (in_sizes[0] + in_sizes[1]) / 4;
        cvt_f32_to_f16<<<(total4 + 255) / 256, 256, 0, stream>>>(
            x1, x2, x1h, x2h, in_sizes[0], in_sizes[1]);
        rowsum_f16<<<(n + 255) / 256, 256, 0, stream>>>(x1h, fA, n);
        rowsum_f16<<<(m + 255) / 256, 256, 0, stream>>>(x2h, fB, m);

        dim3 grid(m / JBL, n / IB);   // 16 x 128 = 2048 blocks
        laplace_wide_kernel<<<grid, 256, 0, stream>>>(x1h, x2h, fA, fB, out, n, m);
    } else {
        dim3 grid(m / 256, n / 256);
        laplace_f32_kernel<<<grid, 256, 0, stream>>>(x1, x2, out, n, m);
    }
}